// Round 1
// baseline (1146.106 us; speedup 1.0000x reference)
//
#include <hip/hip_runtime.h>
#include <cstddef>

#define HW 16384
#define WID 128

__device__ __forceinline__ int wstart(int i) {
    // K=7, DIL=2, L=128: nh*d = 6
    if (i < 6) return i & 1;
    if (i >= 122) return 114 + (i & 1);
    return i - 6;
}
__device__ __forceinline__ int pbstart(int i) {
    if (i < 6) return 6 - (i >> 1);
    if (i >= 122) return (127 - i) >> 1;
    return 3;
}

// ---------------- GEMM: Y[b,m,n] = sum_k W[m,k] * X[b,k,n] + bias[m] ----------------
// 64x64 tile, BK=16, 256 threads, 4x4 per thread.
__global__ __launch_bounds__(256) void gemm_k(const float* __restrict__ Wm,
                                              const float* __restrict__ X,
                                              const float* __restrict__ bias,
                                              float* __restrict__ Y,
                                              int M, int N, int Kd) {
    __shared__ float As[16][68];
    __shared__ float Bs[16][68];
    const int bz = blockIdx.z;
    const float* Xb = X + (size_t)bz * Kd * N;
    float* Yb = Y + (size_t)bz * M * N;
    const int m0 = blockIdx.y * 64, n0 = blockIdx.x * 64;
    const int t = threadIdx.x;
    const int tx = t & 15, ty = t >> 4;
    const int ar = t >> 2, ac = (t & 3) * 4;
    const int br = t >> 4, bc = (t & 15) * 4;

    float acc[4][4] = {};
    for (int k0 = 0; k0 < Kd; k0 += 16) {
        float4 av = *(const float4*)(Wm + (size_t)(m0 + ar) * Kd + k0 + ac);
        float4 bv = *(const float4*)(Xb + (size_t)(k0 + br) * N + n0 + bc);
        As[ac + 0][ar] = av.x;
        As[ac + 1][ar] = av.y;
        As[ac + 2][ar] = av.z;
        As[ac + 3][ar] = av.w;
        *(float4*)&Bs[br][bc] = bv;
        __syncthreads();
#pragma unroll
        for (int kk = 0; kk < 16; kk++) {
            float a4[4], b4[4];
            *(float4*)a4 = *(const float4*)&As[kk][ty * 4];
            *(float4*)b4 = *(const float4*)&Bs[kk][tx * 4];
#pragma unroll
            for (int mi = 0; mi < 4; mi++)
#pragma unroll
                for (int ni = 0; ni < 4; ni++)
                    acc[mi][ni] = fmaf(a4[mi], b4[ni], acc[mi][ni]);
        }
        __syncthreads();
    }
#pragma unroll
    for (int mi = 0; mi < 4; mi++) {
        int row = m0 + ty * 4 + mi;
        float bsv = bias[row];
        float4 r;
        r.x = acc[mi][0] + bsv;
        r.y = acc[mi][1] + bsv;
        r.z = acc[mi][2] + bsv;
        r.w = acc[mi][3] + bsv;
        *(float4*)&Yb[(size_t)row * N + n0 + tx * 4] = r;
    }
}

// ---------------- RoPE in-place on q (scaled) and k ----------------
// thread = (s in {q,k}, b, pixel). 131072 threads total.
__global__ __launch_bounds__(256) void rope_k(float* __restrict__ qkv,
                                              const float* __restrict__ sinp,
                                              const float* __restrict__ cosp) {
    int t = blockIdx.x * 256 + threadIdx.x;
    int p = t & (HW - 1);
    int b = (t >> 14) & 3;
    int s = t >> 16;  // 0 = q, 1 = k
    float sn[32], cs[32];
#pragma unroll
    for (int d4 = 0; d4 < 8; d4++) {
        *(float4*)&sn[d4 * 4] = *(const float4*)&sinp[(size_t)p * 32 + d4 * 4];
        *(float4*)&cs[d4 * 4] = *(const float4*)&cosp[(size_t)p * 32 + d4 * 4];
    }
    const float scale = s ? 1.0f : 0.17677669529663687f;  // 32^-0.5 for q
    float* base = qkv + ((size_t)b * 768 + s * 256) * HW + p;
    for (int n = 0; n < 8; n++) {
        float* hb = base + (size_t)n * 32 * HW;
#pragma unroll
        for (int d = 0; d < 32; d += 2) {
            float a = hb[(size_t)d * HW];
            float bb = hb[(size_t)(d + 1) * HW];
            float ra = (a * cs[d] - bb * sn[d]) * scale;
            float rb = (bb * cs[d + 1] + a * sn[d + 1]) * scale;
            hb[(size_t)d * HW] = ra;
            hb[(size_t)(d + 1) * HW] = rb;
        }
    }
}

// ---------------- Neighborhood attention ----------------
// block = 256 threads = 2 rows x 128 cols of pixels; grid (64, NH, B)
__global__ __launch_bounds__(256) void attn_k(const float* __restrict__ qkv,
                                              const float* __restrict__ rpb,
                                              float* __restrict__ out) {
    const int t = threadIdx.x;
    const int i = blockIdx.x * 2 + (t >> 7);
    const int j = t & 127;
    const int n = blockIdx.y, b = blockIdx.z;
    const float* qb = qkv + ((size_t)b * 768 + n * 32) * HW;
    const float* kb = qb + (size_t)256 * HW;
    const float* vb = qb + (size_t)512 * HW;
    const int p = i * WID + j;

    const int hs = wstart(i), ws_ = wstart(j);
    const int ph = pbstart(i), pw = pbstart(j);

    float sc[49];
    const float* rp = rpb + n * 169;
#pragma unroll
    for (int ki = 0; ki < 7; ki++)
#pragma unroll
        for (int kj = 0; kj < 7; kj++)
            sc[ki * 7 + kj] = rp[(ph + ki) * 13 + (pw + kj)];

    // QK^T
    for (int c = 0; c < 32; c++) {
        float qc = qb[(size_t)c * HW + p];
        const float* krow = kb + (size_t)c * HW + hs * WID + ws_;
#pragma unroll
        for (int ki = 0; ki < 7; ki++) {
            const float* kr = krow + ki * 2 * WID;
#pragma unroll
            for (int kj = 0; kj < 7; kj++)
                sc[ki * 7 + kj] = fmaf(qc, kr[kj * 2], sc[ki * 7 + kj]);
        }
    }

    // softmax over 49
    float mx = sc[0];
#pragma unroll
    for (int u = 1; u < 49; u++) mx = fmaxf(mx, sc[u]);
    float sum = 0.0f;
#pragma unroll
    for (int u = 0; u < 49; u++) {
        sc[u] = __expf(sc[u] - mx);
        sum += sc[u];
    }
    float inv = 1.0f / sum;

    // PV, store immediately per channel
    float* ob = out + ((size_t)b * 256 + n * 32) * HW + p;
    for (int c = 0; c < 32; c++) {
        float oc = 0.0f;
        const float* vrow = vb + (size_t)c * HW + hs * WID + ws_;
#pragma unroll
        for (int ki = 0; ki < 7; ki++) {
            const float* vr = vrow + ki * 2 * WID;
#pragma unroll
            for (int kj = 0; kj < 7; kj++)
                oc = fmaf(sc[ki * 7 + kj], vr[kj * 2], oc);
        }
        ob[(size_t)c * HW] = oc * inv;
    }
}

// ---------------- LePE depthwise 5x5 conv, accumulate into attn output ----------------
__global__ __launch_bounds__(256) void lepe_k(const float* __restrict__ qkv,
                                              const float* __restrict__ wl,
                                              const float* __restrict__ bl,
                                              float* __restrict__ out) {
    size_t t = (size_t)blockIdx.x * 256 + threadIdx.x;  // 16,777,216 total
    int p = (int)(t & (HW - 1));
    int ch = (int)((t >> 14) & 255);
    int b = (int)(t >> 22);
    int i = p >> 7, j = p & 127;
    const float* v = qkv + ((size_t)b * 768 + 512 + ch) * HW;
    const float* w = wl + ch * 25;
    float acc = bl[ch];
#pragma unroll
    for (int di = 0; di < 5; di++) {
        int ii = i + di - 2;
        if ((unsigned)ii < 128u) {
#pragma unroll
            for (int dj = 0; dj < 5; dj++) {
                int jj = j + dj - 2;
                if ((unsigned)jj < 128u)
                    acc = fmaf(w[di * 5 + dj], v[ii * WID + jj], acc);
            }
        }
    }
    out[((size_t)b * 256 + ch) * HW + p] += acc;
}

extern "C" void kernel_launch(void* const* d_in, const int* in_sizes, int n_in,
                              void* d_out, int out_size, void* d_ws, size_t ws_size,
                              hipStream_t stream) {
    const float* x = (const float*)d_in[0];
    const float* sinp = (const float*)d_in[1];
    const float* cosp = (const float*)d_in[2];
    const float* w_qkv = (const float*)d_in[3];
    const float* b_qkv = (const float*)d_in[4];
    const float* w_lepe = (const float*)d_in[5];
    const float* b_lepe = (const float*)d_in[6];
    const float* w_proj = (const float*)d_in[7];
    const float* b_proj = (const float*)d_in[8];
    const float* rpb = (const float*)d_in[9];
    float* out = (float*)d_out;

    float* qkvb = (float*)d_ws;            // 4*768*16384 floats = 201 MB
    float* attno = qkvb + (size_t)50331648; // 4*256*16384 floats = 67 MB

    // 1) QKV projection: qkv[b, 0:768, p]
    gemm_k<<<dim3(256, 12, 4), 256, 0, stream>>>(w_qkv, x, b_qkv, qkvb, 768, HW, 256);
    // 2) RoPE on q and k (in place), q scaled by 1/sqrt(32)
    rope_k<<<dim3(512), 256, 0, stream>>>(qkvb, sinp, cosp);
    // 3) neighborhood attention -> attno[b, 0:256, p]
    attn_k<<<dim3(64, 8, 4), 256, 0, stream>>>(qkvb, rpb, attno);
    // 4) LePE depthwise conv += into attno
    lepe_k<<<dim3(65536), 256, 0, stream>>>(qkvb, w_lepe, b_lepe, attno);
    // 5) output projection -> d_out
    gemm_k<<<dim3(256, 4, 4), 256, 0, stream>>>(w_proj, attno, b_proj, out, 256, HW, 256);
}